// Round 1
// baseline (944.257 us; speedup 1.0000x reference)
//
#include <hip/hip_runtime.h>

#define U_N 8192
#define I_N 16384

typedef float f4 __attribute__((ext_vector_type(4)));
typedef unsigned long long u64;

// float -> OCP e4m3fn byte, RTNE, saturating to +-448. Pure bit/math version
// (no dependency on hip_fp8.h semantics).
__device__ __forceinline__ unsigned char f2e4m3(float x) {
  unsigned char sign = (x < 0.f) ? 0x80 : 0x00;
  float ax = fabsf(x);
  unsigned char code;
  if (ax >= 448.f) {
    code = 0x7E;                       // max finite
  } else if (ax < 0.015625f) {         // below 2^-6: subnormal grid 2^-9
    int q = (int)rintf(ax * 512.f);    // 0..8 (8 rolls into first normal 0x08)
    code = (unsigned char)q;
  } else {
    int e; float f = frexpf(ax, &e);   // ax = f * 2^e, f in [0.5,1)
    int q = (int)rintf(f * 16.f);      // 8..16
    if (q == 16) { q = 8; e += 1; }
    code = (unsigned char)(((e + 6) << 3) | (q - 8));
  }
  return sign | code;
}

// Scales: S * 2^17 (max 16), u0/i0 * 2^9 (max ~14), propagated vectors * 2^16.
#define SCALE_S   131072.f
#define SCALE_V0  512.f
#define SCALE_VK  65536.f

// ---------------------------------------------------------------------------
// convert: S fp32 -> S fp8 (row-major), u0 -> wT0[e][r], i0 -> vT0[e][c]
// grid: 1024 (u0) + 2048 (i0) + [32768 (S) when full workspace available]
// ---------------------------------------------------------------------------
__global__ __launch_bounds__(256)
void convert_kernel(const float* __restrict__ Sf,
                    const float* __restrict__ u0,
                    const float* __restrict__ i0,
                    unsigned char* __restrict__ S8,
                    unsigned char* __restrict__ wT0,
                    unsigned char* __restrict__ vT0)
{
  const int tid = threadIdx.x;
  const int bid = blockIdx.x;
  if (bid < 1024) {
    const int idx = bid * 256 + tid;                 // over U_N*32
    wT0[(idx & 31) * U_N + (idx >> 5)] = f2e4m3(u0[idx] * SCALE_V0);
  } else if (bid < 3072) {
    const int idx = (bid - 1024) * 256 + tid;        // over I_N*32
    vT0[(idx & 31) * I_N + (idx >> 5)] = f2e4m3(i0[idx] * SCALE_V0);
  } else {
    const size_t base = (size_t)(bid - 3072) * 4096 + (size_t)tid * 16;
    const float4* src = (const float4*)(Sf + base);
    union { unsigned char b[16]; uint4 v; } out;
#pragma unroll
    for (int g = 0; g < 4; ++g) {
      float4 f = src[g];
      out.b[g * 4 + 0] = f2e4m3(f.x * SCALE_S);
      out.b[g * 4 + 1] = f2e4m3(f.y * SCALE_S);
      out.b[g * 4 + 2] = f2e4m3(f.z * SCALE_S);
      out.b[g * 4 + 3] = f2e4m3(f.w * SCALE_S);
    }
    *(uint4*)&S8[base] = out.v;
  }
}

// ---------------------------------------------------------------------------
// pass kernel: one launch computes BOTH products of a round via MFMA fp8.
//   blocks [0,1024):    R: u_part[ks][r][e] = sum_{c in ks-range} S[r][c]*i_k[c][e]
//   blocks [1024,2048): C: i_part[rs][c][e] = sum_{r in rs-range} S[r][c]*u_k[r][e]
// A-frag layout (16x16x32): lane holds A[m=lane&15][k=quad*8+j], j = byte 0..7
// B-frag:                   lane holds B[k=quad*8+j][n=lane&15]
// D:                        col = lane&15, row = quad*4 + reg
// ---------------------------------------------------------------------------
template <bool F8>
__global__ __launch_bounds__(256, 4)
void pass_kernel(const unsigned char* __restrict__ S8,
                 const float* __restrict__ Sf,
                 const unsigned char* __restrict__ vT,   // [32][I_N] = i_k^T, scaled
                 const unsigned char* __restrict__ wT,   // [32][U_N] = u_k^T, scaled
                 float* __restrict__ u_part,             // [8][U_N][32]
                 float* __restrict__ i_part,             // [4][I_N][32]
                 float descale)
{
  __shared__ unsigned char smem[16896];
  const int tid = threadIdx.x;
  const int lane = tid & 63;
  const int wave = tid >> 6;
  const int m = lane & 15;
  const int quad = lane >> 4;
  const int bid = blockIdx.x;

  if (bid < 1024) {
    // ---------------- R product ----------------
    const int rg = bid & 127, ks = bid >> 7;
    const int r0 = rg * 64 + wave * 16;
    const int cbase = ks * 2048;
    f4 acc0 = {0.f, 0.f, 0.f, 0.f};
    f4 acc1 = {0.f, 0.f, 0.f, 0.f};
    for (int ch = 0; ch < 4; ++ch) {
      const int cb = cbase + ch * 512;
      // stage vT[32][cb..cb+512] -> smem[e*528 + x]
#pragma unroll
      for (int it = 0; it < 4; ++it) {
        const int idx = it * 256 + tid;
        const int e = idx >> 5;
        const int o = (idx & 31) * 16;
        *(uint4*)&smem[e * 528 + o] = *(const uint4*)&vT[(size_t)e * I_N + cb + o];
      }
      __syncthreads();
#pragma unroll
      for (int kk = 0; kk < 512; kk += 32) {
        long a;
        if (F8) {
          a = *(const long*)(S8 + (size_t)(r0 + m) * I_N + cb + kk + quad * 8);
        } else {
          const float* p = Sf + (size_t)(r0 + m) * I_N + cb + kk + quad * 8;
          u64 av = 0;
#pragma unroll
          for (int j = 0; j < 8; ++j) av |= (u64)f2e4m3(p[j] * SCALE_S) << (8 * j);
          a = (long)av;
        }
        const long b0 = *(const long*)&smem[m * 528 + kk + quad * 8];
        const long b1 = *(const long*)&smem[(m + 16) * 528 + kk + quad * 8];
        acc0 = __builtin_amdgcn_mfma_f32_16x16x32_fp8_fp8(a, b0, acc0, 0, 0, 0);
        acc1 = __builtin_amdgcn_mfma_f32_16x16x32_fp8_fp8(a, b1, acc1, 0, 0, 0);
      }
      __syncthreads();
    }
    float* dst = u_part + (size_t)ks * (U_N * 32);
#pragma unroll
    for (int i2 = 0; i2 < 4; ++i2) {
      const int r = r0 + quad * 4 + i2;
      dst[r * 32 + m]      = acc0[i2] * descale;
      dst[r * 32 + 16 + m] = acc1[i2] * descale;
    }
  } else {
    // ---------------- C product ----------------
    const int b = bid - 1024;
    const int cg = b & 255, rs = b >> 8;
    const int c0 = cg * 64;
    const int rbase = rs * 2048;
    const int cw = wave * 16;
    unsigned char* stile = smem;          // [128][72] natural layout, 9216 B
    unsigned char* wlds  = smem + 9216;   // [32][144], 4608 B
    f4 acc0 = {0.f, 0.f, 0.f, 0.f};
    f4 acc1 = {0.f, 0.f, 0.f, 0.f};
    for (int ch = 0; ch < 16; ++ch) {
      const int rb = rbase + ch * 128;
      // stage S[rb..rb+128][c0..c0+64] (8 KB)
#pragma unroll
      for (int it = 0; it < 4; ++it) {
        const int idx = it * 256 + tid;
        const int rr = idx >> 3;
        const int o = (idx & 7) * 8;
        if (F8) {
          *(u64*)&stile[rr * 72 + o] =
              *(const u64*)(S8 + (size_t)(rb + rr) * I_N + c0 + o);
        } else {
          const float* p = Sf + (size_t)(rb + rr) * I_N + c0 + o;
          u64 v = 0;
#pragma unroll
          for (int j = 0; j < 8; ++j) v |= (u64)f2e4m3(p[j] * SCALE_S) << (8 * j);
          *(u64*)&stile[rr * 72 + o] = v;
        }
      }
      // stage wT[32][rb..rb+128] (4 KB)
      {
        const int e = tid >> 3;
        const int o = (tid & 7) * 16;
        *(uint4*)&wlds[e * 144 + o] = *(const uint4*)&wT[(size_t)e * U_N + rb + o];
      }
      __syncthreads();
#pragma unroll
      for (int kk = 0; kk < 128; kk += 32) {
        u64 av = 0;
#pragma unroll
        for (int j = 0; j < 8; ++j)
          av |= (u64)stile[(kk + quad * 8 + j) * 72 + cw + m] << (8 * j);
        const long b0 = *(const long*)&wlds[m * 144 + kk + quad * 8];
        const long b1 = *(const long*)&wlds[(m + 16) * 144 + kk + quad * 8];
        acc0 = __builtin_amdgcn_mfma_f32_16x16x32_fp8_fp8((long)av, b0, acc0, 0, 0, 0);
        acc1 = __builtin_amdgcn_mfma_f32_16x16x32_fp8_fp8((long)av, b1, acc1, 0, 0, 0);
      }
      __syncthreads();
    }
    float* dst = i_part + (size_t)rs * (I_N * 32);
#pragma unroll
    for (int i2 = 0; i2 < 4; ++i2) {
      const int c = c0 + cw + quad * 4 + i2;
      dst[c * 32 + m]      = acc0[i2] * descale;
      dst[c * 32 + 16 + m] = acc1[i2] * descale;
    }
  }
}

// ---------------------------------------------------------------------------
// reduce: sum split-K partials, maintain fp32 running sums, emit next-round
// quantized transposed vectors, and on round 3 write the final outputs.
// grid: 3072 x 256 == U_N*32 + I_N*32 threads
// ---------------------------------------------------------------------------
__global__ __launch_bounds__(256)
void reduce_kernel(const float* __restrict__ u_part, const float* __restrict__ i_part,
                   const float* __restrict__ u0, const float* __restrict__ i0,
                   float* __restrict__ acc_u, float* __restrict__ acc_i,
                   unsigned char* __restrict__ wT, unsigned char* __restrict__ vT,
                   float* __restrict__ out_u, float* __restrict__ out_i,
                   int round)
{
  const int gid = blockIdx.x * 256 + threadIdx.x;
  if (gid < U_N * 32) {
    float s = 0.f;
#pragma unroll
    for (int sp = 0; sp < 8; ++sp) s += u_part[(size_t)sp * (U_N * 32) + gid];
    if (round == 1)      acc_u[gid] = u0[gid] + s;
    else if (round == 2) acc_u[gid] += s;
    else                 out_u[gid] = (acc_u[gid] + s) * 0.25f;
    if (round < 3) wT[(gid & 31) * U_N + (gid >> 5)] = f2e4m3(s * SCALE_VK);
  } else {
    const int g = gid - U_N * 32;
    float s = 0.f;
#pragma unroll
    for (int sp = 0; sp < 4; ++sp) s += i_part[(size_t)sp * (I_N * 32) + g];
    if (round == 1)      acc_i[g] = i0[g] + s;
    else if (round == 2) acc_i[g] += s;
    else                 out_i[g] = (acc_i[g] + s) * 0.25f;
    if (round < 3) vT[(g & 31) * I_N + (g >> 5)] = f2e4m3(s * SCALE_VK);
  }
}

extern "C" void kernel_launch(void* const* d_in, const int* in_sizes, int n_in,
                              void* d_out, int out_size, void* d_ws, size_t ws_size,
                              hipStream_t stream) {
  const float* u0 = (const float*)d_in[0];   // [8192][32]
  const float* i0 = (const float*)d_in[1];   // [16384][32]
  const float* Sf = (const float*)d_in[2];   // [8192][16384]
  float* out_u = (float*)d_out;
  float* out_i = out_u + U_N * 32;
  unsigned char* ws = (unsigned char*)d_ws;

  const size_t S8_BYTES = (size_t)U_N * I_N;        // 128 MB
  const size_t SMALL_BYTES = 20709376;              // partials + accs + vTs
  const bool f8 = ws_size >= S8_BYTES + SMALL_BYTES;

  unsigned char* S8;
  unsigned char* cur;
  if (f8) { S8 = ws; cur = ws + S8_BYTES; }
  else    { S8 = nullptr; cur = ws; }
  float* u_part = (float*)cur;                      // 8 * U_N*32 floats
  float* i_part = u_part + 8 * U_N * 32;            // 4 * I_N*32 floats
  float* acc_u  = i_part + 4 * I_N * 32;
  float* acc_i  = acc_u + U_N * 32;
  unsigned char* wT = (unsigned char*)(acc_i + I_N * 32);   // 32*U_N bytes
  unsigned char* vT = wT + 32 * U_N;                        // 32*I_N bytes

  convert_kernel<<<f8 ? 35840 : 3072, 256, 0, stream>>>(Sf, u0, i0, S8, wT, vT);

  const float ds1 = 1.f / (SCALE_S * SCALE_V0);
  const float dsk = 1.f / (SCALE_S * SCALE_VK);
  for (int round = 1; round <= 3; ++round) {
    const float ds = (round == 1) ? ds1 : dsk;
    if (f8)
      pass_kernel<true><<<2048, 256, 0, stream>>>(S8, nullptr, vT, wT, u_part, i_part, ds);
    else
      pass_kernel<false><<<2048, 256, 0, stream>>>(nullptr, Sf, vT, wT, u_part, i_part, ds);
    reduce_kernel<<<3072, 256, 0, stream>>>(u_part, i_part, u0, i0, acc_u, acc_i,
                                            wT, vT, out_u, out_i, round);
  }
}